// Round 2
// baseline (376.271 us; speedup 1.0000x reference)
//
#include <hip/hip_runtime.h>
#include <stdint.h>

typedef __attribute__((ext_vector_type(8))) short bf16x8;   // 8 bf16 in 4 VGPRs
typedef __attribute__((ext_vector_type(4))) float f32x4;

#define M_DIM 8192
#define N_DIM 8192
#define K_DIM 2048
#define BK 32
#define NT (K_DIM / BK)   // 64 K-tiles

__device__ __forceinline__ unsigned short f2bf(float f) {
  uint32_t b = __builtin_bit_cast(uint32_t, f);
  b = (b + 0x7FFFu + ((b >> 16) & 1u)) >> 16;   // round-to-nearest-even
  return (unsigned short)b;
}

__device__ __forceinline__ unsigned short tern(float w) {
  return (fabsf(w) > 0.4f) ? ((w > 0.f) ? (unsigned short)0x3F80 : (unsigned short)0xBF80)
                           : (unsigned short)0;
}

// Fused pre-pass: x (fp32) -> bf16, W (fp32) -> ternary bf16.
__global__ void tl_convert(const float* __restrict__ x, const float* __restrict__ W,
                           unsigned short* __restrict__ xb, unsigned short* __restrict__ wb,
                           int n4) {
  int i = blockIdx.x * blockDim.x + threadIdx.x;
  int stride = gridDim.x * blockDim.x;
  for (; i < n4; i += stride) {
    float4 v = reinterpret_cast<const float4*>(x)[i];
    ushort4 o;
    o.x = f2bf(v.x); o.y = f2bf(v.y); o.z = f2bf(v.z); o.w = f2bf(v.w);
    reinterpret_cast<ushort4*>(xb)[i] = o;
    float4 w = reinterpret_cast<const float4*>(W)[i];
    ushort4 t;
    t.x = tern(w.x); t.y = tern(w.y); t.z = tern(w.z); t.w = tern(w.w);
    reinterpret_cast<ushort4*>(wb)[i] = t;
  }
}

// C[t,o] = sum_k A[t,k]*B[o,k]. A:[M,K] bf16, B:[N,K] bf16, both row-major.
// 256x256 tile, BK=32, 8 waves (2M x 4N), per-wave 128x64 via 8x4 frags.
// 3-buffer LDS pipeline (96 KiB): while computing tile T, stage T+2.
// Counted vmcnt(4) at tile boundary (drains T+1 only). setprio around MFMA.
// XOR swizzle (row&3)<<3 half-units, applied on global SOURCE and ds_read addr.
__global__ __launch_bounds__(512, 2)
void tl_gemm(const unsigned short* __restrict__ A, const unsigned short* __restrict__ B,
             float* __restrict__ C) {
  __shared__ unsigned short sA[3][256 * BK];   // 3 x 16 KiB
  __shared__ unsigned short sB[3][256 * BK];   // 3 x 16 KiB

  const int tid  = threadIdx.x;
  const int lane = tid & 63;
  const int w    = tid >> 6;       // wave 0..7
  const int wm   = w >> 2;         // 0..1 -> rows wm*128
  const int wn   = w & 3;          // 0..3 -> cols wn*64

  // XCD-aware bijective swizzle: nwg = 1024 = 8 * 128
  int bid = blockIdx.x;
  int swz = (bid & 7) * 128 + (bid >> 3);
  const int tm = swz >> 5;         // 32 tiles per dim
  const int tn = swz & 31;
  const size_t brow = (size_t)tm * 256;
  const size_t bcol = (size_t)tn * 256;

  const int fr = lane & 15;        // fragment row index
  const int k8 = lane >> 4;        // k slot 0..3

  // ---- precomputed per-lane LDS read offsets (swizzled) ----
  // row&3 == fr&3 for all fragment rows, so the XOR term is lane-constant.
  const int colh_rd = (k8 * 8) ^ ((fr & 3) << 3);              // half-elems
  const int base_a  = (wm * 128 + fr) * BK + colh_rd;           // + mi*16*BK
  const int base_b  = (wn * 64  + fr) * BK + colh_rd;           // + ni*16*BK

  // ---- precomputed per-lane staging addresses ----
  // each load: 16 rows x 64B; lane l -> row (l>>2), byte col (l&3)*16
  const int st_r   = lane >> 2;                                 // 0..15
  const int st_colh = ((lane & 3) * 8) ^ ((st_r & 3) << 3);     // swizzled source col
  const unsigned short* gA0 = A + (brow + w * 32 + st_r) * (size_t)K_DIM + st_colh;
  const unsigned short* gB0 = B + (bcol + w * 32 + st_r) * (size_t)K_DIM + st_colh;

#define STAGE_A(bufi, kt, j) do {                                                   \
    const unsigned short* g = gA0 + (size_t)(j) * 16 * K_DIM + (kt);                \
    unsigned short* l = (unsigned short*)&sA[bufi][(w * 32 + (j) * 16) * BK];       \
    __builtin_amdgcn_global_load_lds((const __attribute__((address_space(1))) void*)g, \
        (__attribute__((address_space(3))) void*)l, 16, 0, 0);                      \
  } while (0)
#define STAGE_B(bufi, kt, j) do {                                                   \
    const unsigned short* g = gB0 + (size_t)(j) * 16 * K_DIM + (kt);                \
    unsigned short* l = (unsigned short*)&sB[bufi][(w * 32 + (j) * 16) * BK];       \
    __builtin_amdgcn_global_load_lds((const __attribute__((address_space(1))) void*)g, \
        (__attribute__((address_space(3))) void*)l, 16, 0, 0);                      \
  } while (0)

  f32x4 acc[8][4];
  #pragma unroll
  for (int i = 0; i < 8; ++i)
    #pragma unroll
    for (int j = 0; j < 4; ++j)
      acc[i][j] = f32x4{0.f, 0.f, 0.f, 0.f};

  // ---- prologue: stage tile 0 -> buf0, tile 1 -> buf1 (4 loads each) ----
  STAGE_A(0, 0, 0); STAGE_A(0, 0, 1); STAGE_B(0, 0, 0); STAGE_B(0, 0, 1);
  STAGE_A(1, BK, 0); STAGE_A(1, BK, 1); STAGE_B(1, BK, 0); STAGE_B(1, BK, 1);
  asm volatile("s_waitcnt vmcnt(4)" ::: "memory");   // tile 0 resident; tile 1 in flight
  __builtin_amdgcn_s_barrier();
  __builtin_amdgcn_sched_barrier(0);

  int cur = 0;
  for (int T = 0; T < NT; ++T) {
    const int nxt = (cur + 2 >= 3) ? cur - 1 : cur + 2;       // (T+2) % 3
    const int kt2 = ((T + 2) & (NT - 1)) * BK;                // wraps; dummy stages land in consumed bufs

    // ================= phase 0: frags m0..3 x n0..3 =================
    bf16x8 av[4], bv[4];
    #pragma unroll
    for (int mi = 0; mi < 4; ++mi)
      av[mi] = *(const bf16x8*)&sA[cur][base_a + mi * 16 * BK];
    #pragma unroll
    for (int ni = 0; ni < 4; ++ni)
      bv[ni] = *(const bf16x8*)&sB[cur][base_b + ni * 16 * BK];
    STAGE_A(nxt, kt2, 0); STAGE_A(nxt, kt2, 1);
    __builtin_amdgcn_s_barrier();
    asm volatile("s_waitcnt lgkmcnt(0)" ::: "memory");
    __builtin_amdgcn_s_setprio(1);
    #pragma unroll
    for (int mi = 0; mi < 4; ++mi)
      #pragma unroll
      for (int ni = 0; ni < 4; ++ni)
        acc[mi][ni] = __builtin_amdgcn_mfma_f32_16x16x32_bf16(av[mi], bv[ni], acc[mi][ni], 0, 0, 0);
    __builtin_amdgcn_s_setprio(0);
    __builtin_amdgcn_s_barrier();

    // ================= phase 1: frags m4..7 x n0..3 =================
    #pragma unroll
    for (int mi = 0; mi < 4; ++mi)
      av[mi] = *(const bf16x8*)&sA[cur][base_a + (mi + 4) * 16 * BK];
    STAGE_B(nxt, kt2, 0); STAGE_B(nxt, kt2, 1);
    // tile boundary: counted wait — drain tile T+1's 4 loads, keep T+2's in flight
    asm volatile("s_waitcnt vmcnt(4)" ::: "memory");
    __builtin_amdgcn_s_barrier();
    __builtin_amdgcn_sched_barrier(0);
    asm volatile("s_waitcnt lgkmcnt(0)" ::: "memory");
    __builtin_amdgcn_s_setprio(1);
    #pragma unroll
    for (int mi = 0; mi < 4; ++mi)
      #pragma unroll
      for (int ni = 0; ni < 4; ++ni)
        acc[mi + 4][ni] = __builtin_amdgcn_mfma_f32_16x16x32_bf16(av[mi], bv[ni], acc[mi + 4][ni], 0, 0, 0);
    __builtin_amdgcn_s_setprio(0);
    __builtin_amdgcn_s_barrier();

    cur = (cur + 1 >= 3) ? 0 : cur + 1;
  }

  // drain dummy stages so no LDS write lands after this workgroup retires
  asm volatile("s_waitcnt vmcnt(0)" ::: "memory");

  // ---- epilogue: C/D layout col = lane&15, row = (lane>>4)*4 + reg ----
  #pragma unroll
  for (int mi = 0; mi < 8; ++mi) {
    #pragma unroll
    for (int ni = 0; ni < 4; ++ni) {
      f32x4 v = acc[mi][ni];
      size_t r0 = brow + wm * 128 + mi * 16 + k8 * 4;
      size_t c0 = bcol + wn * 64 + ni * 16 + fr;
      #pragma unroll
      for (int r = 0; r < 4; ++r)
        C[(r0 + r) * N_DIM + c0] = v[r];
    }
  }
#undef STAGE_A
#undef STAGE_B
}

// Fallback (only if ws_size is unexpectedly small): fused ternarize + fp32 tiled GEMM.
__global__ void tl_naive(const float* __restrict__ x, const float* __restrict__ W,
                         float* __restrict__ out) {
  __shared__ float sx[16][17];
  __shared__ float sw[16][17];
  int tx = threadIdx.x, ty = threadIdx.y;
  int row = blockIdx.y * 16 + ty;
  int col = blockIdx.x * 16 + tx;
  float acc = 0.f;
  for (int kt = 0; kt < K_DIM; kt += 16) {
    sx[ty][tx] = x[(size_t)row * K_DIM + kt + tx];
    float wv = W[(size_t)(blockIdx.x * 16 + ty) * K_DIM + kt + tx];
    sw[ty][tx] = (fabsf(wv) > 0.4f) ? ((wv > 0.f) ? 1.f : -1.f) : 0.f;
    __syncthreads();
    #pragma unroll
    for (int k = 0; k < 16; ++k) acc += sx[ty][k] * sw[tx][k];
    __syncthreads();
  }
  out[(size_t)row * N_DIM + col] = acc;
}

extern "C" void kernel_launch(void* const* d_in, const int* in_sizes, int n_in,
                              void* d_out, int out_size, void* d_ws, size_t ws_size,
                              hipStream_t stream) {
  const float* x = (const float*)d_in[0];
  const float* W = (const float*)d_in[1];
  float* out = (float*)d_out;

  const size_t xb_elems = (size_t)M_DIM * K_DIM;
  const size_t wb_elems = (size_t)N_DIM * K_DIM;
  const size_t need = (xb_elems + wb_elems) * sizeof(unsigned short);   // 64 MiB

  if (ws_size >= need) {
    unsigned short* xb = (unsigned short*)d_ws;
    unsigned short* wb = xb + xb_elems;
    int n4 = (int)(xb_elems / 4);
    tl_convert<<<2048, 256, 0, stream>>>(x, W, xb, wb, n4);
    tl_gemm<<<1024, 512, 0, stream>>>(xb, wb, out);
  } else {
    dim3 g(N_DIM / 16, M_DIM / 16), b(16, 16);
    tl_naive<<<g, b, 0, stream>>>(x, W, out);
  }
}

// Round 3
// 364.036 us; speedup vs baseline: 1.0336x; 1.0336x over previous
//
#include <hip/hip_runtime.h>
#include <stdint.h>

typedef __attribute__((ext_vector_type(8))) short bf16x8;   // 8 bf16 in 4 VGPRs
typedef __attribute__((ext_vector_type(4))) float f32x4;

#define M_DIM 8192
#define N_DIM 8192
#define K_DIM 2048
#define BK 32
#define NT (K_DIM / BK)   // 64 K-tiles

__device__ __forceinline__ unsigned short f2bf(float f) {
  uint32_t b = __builtin_bit_cast(uint32_t, f);
  b = (b + 0x7FFFu + ((b >> 16) & 1u)) >> 16;   // round-to-nearest-even
  return (unsigned short)b;
}

__device__ __forceinline__ unsigned short tern(float w) {
  return (fabsf(w) > 0.4f) ? ((w > 0.f) ? (unsigned short)0x3F80 : (unsigned short)0xBF80)
                           : (unsigned short)0;
}

// Fused pre-pass: x (fp32) -> bf16, W (fp32) -> ternary bf16.
__global__ void tl_convert(const float* __restrict__ x, const float* __restrict__ W,
                           unsigned short* __restrict__ xb, unsigned short* __restrict__ wb,
                           int n4) {
  int i = blockIdx.x * blockDim.x + threadIdx.x;
  int stride = gridDim.x * blockDim.x;
  for (; i < n4; i += stride) {
    float4 v = reinterpret_cast<const float4*>(x)[i];
    ushort4 o;
    o.x = f2bf(v.x); o.y = f2bf(v.y); o.z = f2bf(v.z); o.w = f2bf(v.w);
    reinterpret_cast<ushort4*>(xb)[i] = o;
    float4 w = reinterpret_cast<const float4*>(W)[i];
    ushort4 t;
    t.x = tern(w.x); t.y = tern(w.y); t.z = tern(w.z); t.w = tern(w.w);
    reinterpret_cast<ushort4*>(wb)[i] = t;
  }
}

// C[t,o] = sum_k A[t,k]*B[o,k]. A:[M,K] bf16, B:[N,K] bf16, row-major.
// 256x256 tile, BK=32, 8 waves (2M x 4N), per-wave 128x64 via 8x4 frags.
// 3-buffer LDS (96 KiB): computing tile T reads buf[T%3]; stages tile T+2 into
// buf[(T+2)%3] (read by nobody until 2 boundary barriers later -> race-free).
// 2 phases per K-tile, 16 MFMA each, setprio around MFMA, counted vmcnt(4)
// once per K-tile (drains T+1's 4 loads, keeps T+2's in flight; never 0).
// Swizzle: colh ^= ((row>>1)&3)<<3. Row stride = 64 B, so row bit0 selects the
// 16-bank half; bits1-2 select the 16B slot -> uniform 8-way (b128 minimum).
__global__ __launch_bounds__(512, 2)
void tl_gemm(const unsigned short* __restrict__ A, const unsigned short* __restrict__ B,
             float* __restrict__ C) {
  __shared__ unsigned short sA[3][256 * BK];   // 3 x 16 KiB
  __shared__ unsigned short sB[3][256 * BK];   // 3 x 16 KiB

  const int tid  = threadIdx.x;
  const int lane = tid & 63;
  const int w    = tid >> 6;       // wave 0..7
  const int wm   = w >> 2;         // 0..1 -> rows wm*128
  const int wn   = w & 3;          // 0..3 -> cols wn*64

  // XCD-aware bijective swizzle: nwg = 1024 = 8 * 128
  int bid = blockIdx.x;
  int swz = (bid & 7) * 128 + (bid >> 3);
  const int tm = swz >> 5;
  const int tn = swz & 31;
  const size_t brow = (size_t)tm * 256;
  const size_t bcol = (size_t)tn * 256;

  const int fr = lane & 15;        // fragment row index
  const int k8 = lane >> 4;        // k slot 0..3

  // ---- LDS read offsets (halves). swizzle uses row bits 1-2 only ----
  const int colh   = (k8 * 8) ^ (((fr >> 1) & 3) << 3);
  const int base_a = (wm * 128 + fr) * BK + colh;     // + mi*16*BK
  const int base_b = (wn * 64  + fr) * BK + colh;     // + ni*16*BK

  // ---- staging: one load = 512 thr x 16B = 128 rows x 64B ----
  // thread: row = lane>>2 (within wave's 16 rows), col slot = lane&3
  const int src_colh = (((lane & 3) ^ ((lane >> 3) & 3)) * 8);  // pre-swizzled source
  const unsigned short* gA0 = A + (brow + w * 16 + (lane >> 2)) * (size_t)K_DIM + src_colh;
  const unsigned short* gB0 = B + (bcol + w * 16 + (lane >> 2)) * (size_t)K_DIM + src_colh;

#define STAGE_A(bufi, kt, j) do {                                                    \
    const unsigned short* g = gA0 + (size_t)(j) * 128 * K_DIM + (kt);                \
    unsigned short* l = (unsigned short*)&sA[bufi][((j) * 128 + w * 16) * BK];       \
    __builtin_amdgcn_global_load_lds((const __attribute__((address_space(1))) void*)g, \
        (__attribute__((address_space(3))) void*)l, 16, 0, 0);                       \
  } while (0)
#define STAGE_B(bufi, kt, j) do {                                                    \
    const unsigned short* g = gB0 + (size_t)(j) * 128 * K_DIM + (kt);                \
    unsigned short* l = (unsigned short*)&sB[bufi][((j) * 128 + w * 16) * BK];       \
    __builtin_amdgcn_global_load_lds((const __attribute__((address_space(1))) void*)g, \
        (__attribute__((address_space(3))) void*)l, 16, 0, 0);                       \
  } while (0)

  f32x4 acc[8][4];
  #pragma unroll
  for (int i = 0; i < 8; ++i)
    #pragma unroll
    for (int j = 0; j < 4; ++j)
      acc[i][j] = f32x4{0.f, 0.f, 0.f, 0.f};

  // ---- prologue: tile 0 -> buf0 (4 loads), tile 1 -> buf1 (4 loads) ----
  STAGE_A(0, 0, 0); STAGE_A(0, 0, 1); STAGE_B(0, 0, 0); STAGE_B(0, 0, 1);
  STAGE_A(1, BK, 0); STAGE_A(1, BK, 1); STAGE_B(1, BK, 0); STAGE_B(1, BK, 1);
  asm volatile("s_waitcnt vmcnt(4)" ::: "memory");   // tile 0 resident; tile 1 in flight
  __builtin_amdgcn_s_barrier();
  __builtin_amdgcn_sched_barrier(0);

  int cur = 0;
  for (int T = 0; T < NT; ++T) {
    const int nxt2 = (cur + 2 >= 3) ? cur - 1 : cur + 2;   // (T+2) % 3
    const int kt2  = ((T + 2) & (NT - 1)) * BK;            // wraps to dummy (harmless)

    bf16x8 av[4], bv[4];

    // ============ phase 1: mi 0..3 x ni 0..3 (16 MFMA) ============
    #pragma unroll
    for (int mi = 0; mi < 4; ++mi)
      av[mi] = *(const bf16x8*)&sA[cur][base_a + mi * 16 * BK];
    #pragma unroll
    for (int ni = 0; ni < 4; ++ni)
      bv[ni] = *(const bf16x8*)&sB[cur][base_b + ni * 16 * BK];
    STAGE_A(nxt2, kt2, 0); STAGE_A(nxt2, kt2, 1);
    __builtin_amdgcn_s_barrier();
    asm volatile("s_waitcnt lgkmcnt(0)" ::: "memory");
    __builtin_amdgcn_sched_barrier(0);
    __builtin_amdgcn_s_setprio(1);
    #pragma unroll
    for (int mi = 0; mi < 4; ++mi)
      #pragma unroll
      for (int ni = 0; ni < 4; ++ni)
        acc[mi][ni] = __builtin_amdgcn_mfma_f32_16x16x32_bf16(av[mi], bv[ni], acc[mi][ni], 0, 0, 0);
    __builtin_amdgcn_s_setprio(0);
    __builtin_amdgcn_s_barrier();

    // ============ phase 2: mi 4..7 x ni 0..3 (16 MFMA, bv reused) ============
    #pragma unroll
    for (int mi = 0; mi < 4; ++mi)
      av[mi] = *(const bf16x8*)&sA[cur][base_a + (mi + 4) * 16 * BK];
    STAGE_B(nxt2, kt2, 0); STAGE_B(nxt2, kt2, 1);
    __builtin_amdgcn_s_barrier();
    asm volatile("s_waitcnt lgkmcnt(0)" ::: "memory");
    __builtin_amdgcn_sched_barrier(0);
    __builtin_amdgcn_s_setprio(1);
    #pragma unroll
    for (int mi = 0; mi < 4; ++mi)
      #pragma unroll
      for (int ni = 0; ni < 4; ++ni)
        acc[mi + 4][ni] = __builtin_amdgcn_mfma_f32_16x16x32_bf16(av[mi], bv[ni], acc[mi + 4][ni], 0, 0, 0);
    __builtin_amdgcn_s_setprio(0);
    // K-tile boundary: drain tile T+1's 4 loads; tile T+2's 4 stay in flight
    asm volatile("s_waitcnt vmcnt(4)" ::: "memory");
    __builtin_amdgcn_s_barrier();
    __builtin_amdgcn_sched_barrier(0);

    cur = (cur + 1 >= 3) ? 0 : cur + 1;
  }

  // drain dummy stages before retiring
  asm volatile("s_waitcnt vmcnt(0)" ::: "memory");

  // ---- epilogue: C/D layout col = lane&15, row = (lane>>4)*4 + reg ----
  #pragma unroll
  for (int mi = 0; mi < 8; ++mi) {
    #pragma unroll
    for (int ni = 0; ni < 4; ++ni) {
      f32x4 v = acc[mi][ni];
      size_t r0 = brow + wm * 128 + mi * 16 + k8 * 4;
      size_t c0 = bcol + wn * 64 + ni * 16 + fr;
      #pragma unroll
      for (int r = 0; r < 4; ++r)
        C[(r0 + r) * N_DIM + c0] = v[r];
    }
  }
#undef STAGE_A
#undef STAGE_B
}

// Fallback (only if ws_size is unexpectedly small): fused ternarize + fp32 tiled GEMM.
__global__ void tl_naive(const float* __restrict__ x, const float* __restrict__ W,
                         float* __restrict__ out) {
  __shared__ float sx[16][17];
  __shared__ float sw[16][17];
  int tx = threadIdx.x, ty = threadIdx.y;
  int row = blockIdx.y * 16 + ty;
  int col = blockIdx.x * 16 + tx;
  float acc = 0.f;
  for (int kt = 0; kt < K_DIM; kt += 16) {
    sx[ty][tx] = x[(size_t)row * K_DIM + kt + tx];
    float wv = W[(size_t)(blockIdx.x * 16 + ty) * K_DIM + kt + tx];
    sw[ty][tx] = (fabsf(wv) > 0.4f) ? ((wv > 0.f) ? 1.f : -1.f) : 0.f;
    __syncthreads();
    #pragma unroll
    for (int k = 0; k < 16; ++k) acc += sx[ty][k] * sw[tx][k];
    __syncthreads();
  }
  out[(size_t)row * N_DIM + col] = acc;
}

extern "C" void kernel_launch(void* const* d_in, const int* in_sizes, int n_in,
                              void* d_out, int out_size, void* d_ws, size_t ws_size,
                              hipStream_t stream) {
  const float* x = (const float*)d_in[0];
  const float* W = (const float*)d_in[1];
  float* out = (float*)d_out;

  const size_t xb_elems = (size_t)M_DIM * K_DIM;
  const size_t wb_elems = (size_t)N_DIM * K_DIM;
  const size_t need = (xb_elems + wb_elems) * sizeof(unsigned short);   // 64 MiB

  if (ws_size >= need) {
    unsigned short* xb = (unsigned short*)d_ws;
    unsigned short* wb = xb + xb_elems;
    int n4 = (int)(xb_elems / 4);
    tl_convert<<<2048, 256, 0, stream>>>(x, W, xb, wb, n4);
    tl_gemm<<<1024, 512, 0, stream>>>(xb, wb, out);
  } else {
    dim3 g(N_DIM / 16, M_DIM / 16), b(16, 16);
    tl_naive<<<g, b, 0, stream>>>(x, W, out);
  }
}